// Round 19
// baseline (696.488 us; speedup 1.0000x reference)
//
#include <hip/hip_runtime.h>

// LSTM B=512,T=512,D=128,H=64,O=1. Gate order i,f,g,o.
// K1: pre = x@Wih0^T + bih0+bhh0 — fp16 MFMA (R15-proven, ~70us).
// K2: R18 AGPR-weight structure, with the serialization bug fixed.
//   R18 post-mortem: aread was `asm volatile` -> strictly ordered + sched
//   fence -> 32 reads/step serialized the fdot2 chains (observed 2722 cyc/step
//   vs ~700 issue-bound estimate, VALUBusy 75%). Fix: aread is now PLAIN asm
//   (no side effects, reorderable; if CSE'd out of the loop the allocator may
//   sink it back — a 1-inst v_accvgpr_read, which is fine, unlike the R3-R11
//   global-load demotion). awrite stays volatile (write-once must survive).
//   dot16 split into 2 independent 4-fdot2 chains (halve dep depth).
//   Else identical to R18/R13: 768 thr, C=2 batches, quad k-split, select-free
//   DPP merges, skewed layers, zl exchange, 2 barriers/step, fp16 weights in
//   AGPRs (32 dwords/thread), h fp16 in LDS.
// ws: 512*512*256*4 = 256 MiB fp32 pre (written by K1, read-only in K2).

#define TSTEPS 512

typedef _Float16 h2v __attribute__((ext_vector_type(2)));
typedef _Float16 half8 __attribute__((ext_vector_type(8)));
typedef __attribute__((ext_vector_type(4))) float facc;
union HU { unsigned u; h2v h; };

__device__ __forceinline__ float sigf(float x){ return 1.0f/(1.0f+__expf(-x)); }
__device__ __forceinline__ float tanh_fast(float x){
  float ax=fabsf(x); float e=__expf(-2.0f*ax); float r=(1.0f-e)/(1.0f+e); return copysignf(r,x);
}
__device__ __forceinline__ unsigned packh(float a, float b){
  unsigned short la = __builtin_bit_cast(unsigned short, (_Float16)a);
  unsigned short lb = __builtin_bit_cast(unsigned short, (_Float16)b);
  return (unsigned)la | ((unsigned)lb << 16);
}
__device__ __forceinline__ float dot2f(unsigned wu, unsigned hu, float acc){
#if __has_builtin(__builtin_amdgcn_fdot2)
  HU w; w.u = wu; HU x; x.u = hu;
  return __builtin_amdgcn_fdot2(w.h, x.h, acc, false);
#else
  HU w; w.u = wu; HU x; x.u = hu;
  acc = fmaf((float)w.h[0], (float)x.h[0], acc);
  acc = fmaf((float)w.h[1], (float)x.h[1], acc);
  return acc;
#endif
}
template<int CTRL>
__device__ __forceinline__ float add_dpp(float a, float b){
  return a + __int_as_float(__builtin_amdgcn_update_dpp(
      0, __float_as_int(b), CTRL, 0xF, 0xF, true));
}
// two independent 4-fdot2 chains (ILP) instead of one 8-deep chain
__device__ __forceinline__ float dot16(uint4 w0, uint4 w1, uint4 h0, uint4 h1){
  float a = 0.0f, b = 0.0f;
  a = dot2f(w0.x, h0.x, a); b = dot2f(w0.y, h0.y, b);
  a = dot2f(w0.z, h0.z, a); b = dot2f(w0.w, h0.w, b);
  a = dot2f(w1.x, h1.x, a); b = dot2f(w1.y, h1.y, b);
  a = dot2f(w1.z, h1.z, a); b = dot2f(w1.w, h1.w, b);
  return a + b;
}
// AGPR park/fetch. Write: volatile (must survive; defines the AGPR once).
// Read: PLAIN asm — reorderable/interleavable by the scheduler (R18's
// volatile reads serialized the whole dot phase).
__device__ __forceinline__ void awrite(unsigned &dst, unsigned v){
  asm volatile("v_accvgpr_write_b32 %0, %1" : "=a"(dst) : "v"(v));
}
__device__ __forceinline__ unsigned aread(const unsigned &src){
  unsigned r;
  asm("v_accvgpr_read_b32 %0, %1" : "=v"(r) : "a"(src));
  return r;
}

// ---------------- K1: input projection GEMM (fp16 MFMA, R15) ----------------
__global__ __launch_bounds__(256) void k_inproj(
    const float* __restrict__ x, const float* __restrict__ W,
    const float* __restrict__ bih, const float* __restrict__ bhh,
    float* __restrict__ pre)
{
    __shared__ __align__(16) _Float16 Ah[64][136];
    __shared__ __align__(16) _Float16 Bh[256][136];
    const int tid = threadIdx.x;
    const long row0 = (long)blockIdx.x * 64;

    {
        const int r = tid >> 2, c0 = (tid & 3) * 32;
        const float4* src = (const float4*)(x + (row0 + r) * 128 + c0);
#pragma unroll
        for (int i = 0; i < 4; ++i) {
            float4 v0 = src[2 * i], v1 = src[2 * i + 1];
            half8 hv = { (_Float16)v0.x, (_Float16)v0.y, (_Float16)v0.z, (_Float16)v0.w,
                         (_Float16)v1.x, (_Float16)v1.y, (_Float16)v1.z, (_Float16)v1.w };
            *(half8*)&Ah[r][c0 + 8 * i] = hv;
        }
    }
    {
        const float4* src = (const float4*)(W + tid * 128);
#pragma unroll
        for (int i = 0; i < 16; ++i) {
            float4 v0 = src[2 * i], v1 = src[2 * i + 1];
            half8 hv = { (_Float16)v0.x, (_Float16)v0.y, (_Float16)v0.z, (_Float16)v0.w,
                         (_Float16)v1.x, (_Float16)v1.y, (_Float16)v1.z, (_Float16)v1.w };
            *(half8*)&Bh[tid][8 * i] = hv;
        }
    }
    __syncthreads();

    const int w  = tid >> 6;
    const int l  = tid & 63;
    const int lm = l & 15;
    const int lk = l >> 4;
    const int n0 = w * 64;

    facc acc[4][4];
#pragma unroll
    for (int mi = 0; mi < 4; ++mi)
#pragma unroll
        for (int ni = 0; ni < 4; ++ni) acc[mi][ni] = (facc){0.f, 0.f, 0.f, 0.f};

#pragma unroll
    for (int ks = 0; ks < 4; ++ks) {
        const int kk = ks * 32 + lk * 8;
        half8 Af[4], Bf[4];
#pragma unroll
        for (int mi = 0; mi < 4; ++mi) Af[mi] = *(const half8*)&Ah[mi * 16 + lm][kk];
#pragma unroll
        for (int ni = 0; ni < 4; ++ni) Bf[ni] = *(const half8*)&Bh[n0 + ni * 16 + lm][kk];
#pragma unroll
        for (int mi = 0; mi < 4; ++mi)
#pragma unroll
            for (int ni = 0; ni < 4; ++ni)
                acc[mi][ni] = __builtin_amdgcn_mfma_f32_16x16x32_f16(
                    Af[mi], Bf[ni], acc[mi][ni], 0, 0, 0);
    }

    float bs[4];
#pragma unroll
    for (int ni = 0; ni < 4; ++ni) {
        const int n = n0 + ni * 16 + lm;
        bs[ni] = bih[n] + bhh[n];
    }
#pragma unroll
    for (int mi = 0; mi < 4; ++mi) {
#pragma unroll
        for (int ni = 0; ni < 4; ++ni) {
            const int n = n0 + ni * 16 + lm;
#pragma unroll
            for (int r = 0; r < 4; ++r) {
                const long row = row0 + mi * 16 + lk * 4 + r;
                pre[row * 256 + n] = acc[mi][ni][r] + bs[ni];
            }
        }
    }
}

// ---------------- K2: fused 2-layer recurrence + head (AGPR weights) --------
__global__
__attribute__((amdgpu_flat_work_group_size(768, 768)))
__attribute__((amdgpu_waves_per_eu(3)))
void k_fused(
    const float* __restrict__ Whh0, const float* __restrict__ Wih1,
    const float* __restrict__ Whh1,
    const float* __restrict__ bih1, const float* __restrict__ bhh1,
    const float* __restrict__ Wfc,  const float* __restrict__ bfc,
    const float* __restrict__ pre,  float* __restrict__ out)
{
    const int tid = threadIdx.x;
    const int ll  = tid & 3;          // lane-in-quad = k-slice index
    const int q   = tid >> 2;         // quad 0..191: rows 4q..4q+3 (global 0..767)
    const int m   = q >> 6;           // matrix: 0=Whh0, 1=Wih1, 2=Whh1
    const int lay = (m == 2) ? 1 : 0; // h layer my matrix consumes
    const int cA  = (ll >> 1) & 1;    // surviving batch slot
    const int cB  = cA ^ 1;

    __shared__ unsigned hp[2][2][2][32];    // 1KB [par][batch][layer] 64 fp16
    __shared__ float zl[2][768];            // 6KB dot results [batch][row]

    // ---- one-time: pack my 4 rows (permuted) x k-slice -> 32 dwords in AGPRs
    unsigned wa[32];
    {
        const float* Wm = (m == 0) ? Whh0 : ((m == 1) ? Wih1 : Whh1);
        const int rofs[4] = { (ll & 1), 2 + (ll & 1), 1 - (ll & 1), 3 - (ll & 1) };
#pragma unroll
        for (int rs = 0; rs < 4; ++rs) {
            const int rr = (4 * q + rofs[rs]) & 255;       // row within matrix
            const float4* src = (const float4*)(Wm + rr * 64 + 16 * ll);
            float4 f0 = src[0], f1 = src[1], f2 = src[2], f3 = src[3];
            awrite(wa[8 * rs + 0], packh(f0.x, f0.y));
            awrite(wa[8 * rs + 1], packh(f0.z, f0.w));
            awrite(wa[8 * rs + 2], packh(f1.x, f1.y));
            awrite(wa[8 * rs + 3], packh(f1.z, f1.w));
            awrite(wa[8 * rs + 4], packh(f2.x, f2.y));
            awrite(wa[8 * rs + 5], packh(f2.z, f2.w));
            awrite(wa[8 * rs + 6], packh(f3.x, f3.y));
            awrite(wa[8 * rs + 7], packh(f3.z, f3.w));
        }
    }
    if (tid < 256) ((unsigned*)hp)[tid] = 0;   // h_{-1}=0 both parities

    // ---- updater role (tid<256): c=batch, l=layer, j=unit ----
    const int c_u = tid >> 7;
    const int l_u = (tid >> 6) & 1;
    const int j_u = tid & 63;
    const long bb = (long)blockIdx.x * 2;
    float bias1v[4] = {0, 0, 0, 0};
    float pc[4] = {0, 0, 0, 0};
    if (tid < 256) {
        if (l_u == 1) {
#pragma unroll
            for (int g = 0; g < 4; ++g) bias1v[g] = bih1[g * 64 + j_u] + bhh1[g * 64 + j_u];
        } else {
            const float* pb = pre + (bb + c_u) * TSTEPS * 256;
#pragma unroll
            for (int g = 0; g < 4; ++g) pc[g] = pb[g * 64 + j_u];   // t=0
        }
    }
    float cst = 0.0f, h1last = 0.0f;
    int p = 0;
    __syncthreads();

#pragma unroll 1
    for (int n = 0; n <= TSTEPS; ++n) {
        // prefetch pre for t=n+1 (layer-0 updaters)
        float pn[4] = {0, 0, 0, 0};
        if (tid < 256 && l_u == 0) {
            const int tn = (n + 1 < TSTEPS) ? n + 1 : 0;
            const float* pb = pre + ((bb + c_u) * TSTEPS + tn) * 256;
#pragma unroll
            for (int g = 0; g < 4; ++g) pn[g] = pb[g * 64 + j_u];
        }

        // ---- h slices (my k-slice, both batch slots): 4 b128, broadcast ----
        uint4 hA0 = *(const uint4*)&hp[p][cA][lay][ll * 8];
        uint4 hA1 = *(const uint4*)&hp[p][cA][lay][ll * 8 + 4];
        uint4 hB0 = *(const uint4*)&hp[p][cB][lay][ll * 8];
        uint4 hB1 = *(const uint4*)&hp[p][cB][lay][ll * 8 + 4];

        // ---- partial dots: weights from AGPRs (plain asm: schedulable) ----
        float pA[4], pB[4];
#pragma unroll
        for (int rs = 0; rs < 4; ++rs) {
            uint4 w0, w1;
            w0.x = aread(wa[8 * rs + 0]); w0.y = aread(wa[8 * rs + 1]);
            w0.z = aread(wa[8 * rs + 2]); w0.w = aread(wa[8 * rs + 3]);
            w1.x = aread(wa[8 * rs + 4]); w1.y = aread(wa[8 * rs + 5]);
            w1.z = aread(wa[8 * rs + 6]); w1.w = aread(wa[8 * rs + 7]);
            pA[rs] = dot16(w0, w1, hA0, hA1);
            pB[rs] = dot16(w0, w1, hB0, hB1);
        }

        // ---- select-free merges ----
        float q0A = add_dpp<0xB1>(pA[0], pA[2]);
        float q1A = add_dpp<0xB1>(pA[1], pA[3]);
        float q0B = add_dpp<0xB1>(pB[0], pB[2]);
        float q1B = add_dpp<0xB1>(pB[1], pB[3]);
        float r0 = add_dpp<0x4E>(q0A, q0B);
        float r1 = add_dpp<0x4E>(q1A, q1B);

        const int R0 = 4 * q + (ll & 1);
        zl[cA][R0]     = r0;
        zl[cA][R0 + 2] = r1;
        __syncthreads();   // zl ready

        // ---- cell updates ----
        if (tid < 256) {
            const bool valid = (l_u == 0) ? (n < TSTEPS) : (n >= 1);
            if (valid) {
                float z[4];
                if (l_u == 0) {
#pragma unroll
                    for (int g = 0; g < 4; ++g) z[g] = pc[g] + zl[c_u][g * 64 + j_u];
                } else {
#pragma unroll
                    for (int g = 0; g < 4; ++g)
                        z[g] = bias1v[g] + zl[c_u][256 + g * 64 + j_u] + zl[c_u][512 + g * 64 + j_u];
                }
                float i_ = sigf(z[0]), f_ = sigf(z[1]), g_ = tanh_fast(z[2]), o_ = sigf(z[3]);
                cst = fmaf(f_, cst, i_ * g_);
                float h = o_ * tanh_fast(cst);
                if (l_u) h1last = h;
                ((unsigned short*)&hp[p ^ 1][c_u][l_u][0])[j_u] =
                    __builtin_bit_cast(unsigned short, (_Float16)h);
            }
        }
        __syncthreads();   // new h visible
        p ^= 1;
        if (tid < 256 && l_u == 0) {
            pc[0] = pn[0]; pc[1] = pn[1]; pc[2] = pn[2]; pc[3] = pn[3];
        }
    }

    // ---- head: out[bb+c] = h1_{T-1} . Wfc + bfc ----
    if (tid < 256 && l_u == 1) {
        float v = h1last * Wfc[j_u];
#pragma unroll
        for (int off = 32; off > 0; off >>= 1) v += __shfl_down(v, off);
        if (j_u == 0) out[bb + c_u] = v + bfc[0];
    }
}

extern "C" void kernel_launch(void* const* d_in, const int* in_sizes, int n_in,
                              void* d_out, int out_size, void* d_ws, size_t ws_size,
                              hipStream_t stream)
{
    const float* x    = (const float*)d_in[0];
    const float* Wih0 = (const float*)d_in[1];
    const float* Whh0 = (const float*)d_in[2];
    const float* bih0 = (const float*)d_in[3];
    const float* bhh0 = (const float*)d_in[4];
    const float* Wih1 = (const float*)d_in[5];
    const float* Whh1 = (const float*)d_in[6];
    const float* bih1 = (const float*)d_in[7];
    const float* bhh1 = (const float*)d_in[8];
    const float* Wfc  = (const float*)d_in[9];
    const float* bfc  = (const float*)d_in[10];
    float* out = (float*)d_out;
    float* pre = (float*)d_ws;  // [B][T][256] fp32 = 256 MiB

    k_inproj<<<4096, 256, 0, stream>>>(x, Wih0, bih0, bhh0, pre);
    k_fused<<<256, 768, 0, stream>>>(Whh0, Wih1, Whh1, bih1, bhh1, Wfc, bfc, pre, out);
}

// Round 20
// 668.552 us; speedup vs baseline: 1.0418x; 1.0418x over previous
//
#include <hip/hip_runtime.h>

// LSTM B=512,T=512,D=128,H=64,O=1. Gate order i,f,g,o.
// K1: pre = x@Wih0^T + bih0+bhh0 — fp16 MFMA (R15-proven, ~70us).
// K2: AGPR-weight recurrence (R18) with step-overhead surgery:
//   (1) all 32 volatile areads batched at step top (R18 interleaved them with
//       dots -> volatile ordering serialized every chain; R19's plain-asm made
//       it worse via CSE/hoist). One 32-inst prologue, then 128 free fdot2.
//   (2) 2-step time unroll, compile-time parity -> hp addresses become
//       ds_read immediate offsets; runtime p and its address math gone.
//   (3) loop: prologue n=0, 255 pairs n=1..510, epilogue n=511, n=512.
//   Dataflow identical to R18/R13 (absmax 4.9e-4): 768 thr, C=2 batches, quad
//   k-split, select-free DPP merges, skewed layers, zl exchange, 2 barriers/step.
// ws: 512*512*256*4 = 256 MiB fp32 pre (written by K1, read-only in K2).

#define TSTEPS 512

typedef _Float16 h2v __attribute__((ext_vector_type(2)));
typedef _Float16 half8 __attribute__((ext_vector_type(8)));
typedef __attribute__((ext_vector_type(4))) float facc;
union HU { unsigned u; h2v h; };

__device__ __forceinline__ float sigf(float x){ return 1.0f/(1.0f+__expf(-x)); }
__device__ __forceinline__ float tanh_fast(float x){
  float ax=fabsf(x); float e=__expf(-2.0f*ax); float r=(1.0f-e)/(1.0f+e); return copysignf(r,x);
}
__device__ __forceinline__ unsigned packh(float a, float b){
  unsigned short la = __builtin_bit_cast(unsigned short, (_Float16)a);
  unsigned short lb = __builtin_bit_cast(unsigned short, (_Float16)b);
  return (unsigned)la | ((unsigned)lb << 16);
}
__device__ __forceinline__ float dot2f(unsigned wu, unsigned hu, float acc){
#if __has_builtin(__builtin_amdgcn_fdot2)
  HU w; w.u = wu; HU x; x.u = hu;
  return __builtin_amdgcn_fdot2(w.h, x.h, acc, false);
#else
  HU w; w.u = wu; HU x; x.u = hu;
  acc = fmaf((float)w.h[0], (float)x.h[0], acc);
  acc = fmaf((float)w.h[1], (float)x.h[1], acc);
  return acc;
#endif
}
template<int CTRL>
__device__ __forceinline__ float add_dpp(float a, float b){
  return a + __int_as_float(__builtin_amdgcn_update_dpp(
      0, __float_as_int(b), CTRL, 0xF, 0xF, true));
}
// two independent 4-fdot2 chains (ILP)
__device__ __forceinline__ float dot16(uint4 w0, uint4 w1, uint4 h0, uint4 h1){
  float a = 0.0f, b = 0.0f;
  a = dot2f(w0.x, h0.x, a); b = dot2f(w0.y, h0.y, b);
  a = dot2f(w0.z, h0.z, a); b = dot2f(w0.w, h0.w, b);
  a = dot2f(w1.x, h1.x, a); b = dot2f(w1.y, h1.y, b);
  a = dot2f(w1.z, h1.z, a); b = dot2f(w1.w, h1.w, b);
  return a + b;
}
// AGPR park/fetch (both volatile: write-once must survive; reads batched at
// step top so their mutual ordering costs one short prologue, not per-dot fences)
__device__ __forceinline__ void awrite(unsigned &dst, unsigned v){
  asm volatile("v_accvgpr_write_b32 %0, %1" : "=a"(dst) : "v"(v));
}
__device__ __forceinline__ unsigned aread(unsigned &src){
  unsigned r;
  asm volatile("v_accvgpr_read_b32 %0, %1" : "=v"(r) : "a"(src));
  return r;
}

// ---------------- K1: input projection GEMM (fp16 MFMA, R15) ----------------
__global__ __launch_bounds__(256) void k_inproj(
    const float* __restrict__ x, const float* __restrict__ W,
    const float* __restrict__ bih, const float* __restrict__ bhh,
    float* __restrict__ pre)
{
    __shared__ __align__(16) _Float16 Ah[64][136];
    __shared__ __align__(16) _Float16 Bh[256][136];
    const int tid = threadIdx.x;
    const long row0 = (long)blockIdx.x * 64;

    {
        const int r = tid >> 2, c0 = (tid & 3) * 32;
        const float4* src = (const float4*)(x + (row0 + r) * 128 + c0);
#pragma unroll
        for (int i = 0; i < 4; ++i) {
            float4 v0 = src[2 * i], v1 = src[2 * i + 1];
            half8 hv = { (_Float16)v0.x, (_Float16)v0.y, (_Float16)v0.z, (_Float16)v0.w,
                         (_Float16)v1.x, (_Float16)v1.y, (_Float16)v1.z, (_Float16)v1.w };
            *(half8*)&Ah[r][c0 + 8 * i] = hv;
        }
    }
    {
        const float4* src = (const float4*)(W + tid * 128);
#pragma unroll
        for (int i = 0; i < 16; ++i) {
            float4 v0 = src[2 * i], v1 = src[2 * i + 1];
            half8 hv = { (_Float16)v0.x, (_Float16)v0.y, (_Float16)v0.z, (_Float16)v0.w,
                         (_Float16)v1.x, (_Float16)v1.y, (_Float16)v1.z, (_Float16)v1.w };
            *(half8*)&Bh[tid][8 * i] = hv;
        }
    }
    __syncthreads();

    const int w  = tid >> 6;
    const int l  = tid & 63;
    const int lm = l & 15;
    const int lk = l >> 4;
    const int n0 = w * 64;

    facc acc[4][4];
#pragma unroll
    for (int mi = 0; mi < 4; ++mi)
#pragma unroll
        for (int ni = 0; ni < 4; ++ni) acc[mi][ni] = (facc){0.f, 0.f, 0.f, 0.f};

#pragma unroll
    for (int ks = 0; ks < 4; ++ks) {
        const int kk = ks * 32 + lk * 8;
        half8 Af[4], Bf[4];
#pragma unroll
        for (int mi = 0; mi < 4; ++mi) Af[mi] = *(const half8*)&Ah[mi * 16 + lm][kk];
#pragma unroll
        for (int ni = 0; ni < 4; ++ni) Bf[ni] = *(const half8*)&Bh[n0 + ni * 16 + lm][kk];
#pragma unroll
        for (int mi = 0; mi < 4; ++mi)
#pragma unroll
            for (int ni = 0; ni < 4; ++ni)
                acc[mi][ni] = __builtin_amdgcn_mfma_f32_16x16x32_f16(
                    Af[mi], Bf[ni], acc[mi][ni], 0, 0, 0);
    }

    float bs[4];
#pragma unroll
    for (int ni = 0; ni < 4; ++ni) {
        const int n = n0 + ni * 16 + lm;
        bs[ni] = bih[n] + bhh[n];
    }
#pragma unroll
    for (int mi = 0; mi < 4; ++mi) {
#pragma unroll
        for (int ni = 0; ni < 4; ++ni) {
            const int n = n0 + ni * 16 + lm;
#pragma unroll
            for (int r = 0; r < 4; ++r) {
                const long row = row0 + mi * 16 + lk * 4 + r;
                pre[row * 256 + n] = acc[mi][ni][r] + bs[ni];
            }
        }
    }
}

// ---------------- K2: fused 2-layer recurrence + head (AGPR, unrolled) ------
__global__
__attribute__((amdgpu_flat_work_group_size(768, 768)))
__attribute__((amdgpu_waves_per_eu(3)))
void k_fused(
    const float* __restrict__ Whh0, const float* __restrict__ Wih1,
    const float* __restrict__ Whh1,
    const float* __restrict__ bih1, const float* __restrict__ bhh1,
    const float* __restrict__ Wfc,  const float* __restrict__ bfc,
    const float* __restrict__ pre,  float* __restrict__ out)
{
    const int tid = threadIdx.x;
    const int ll  = tid & 3;
    const int q   = tid >> 2;
    const int m   = q >> 6;           // matrix: 0=Whh0, 1=Wih1, 2=Whh1
    const int lay = (m == 2) ? 1 : 0;
    const int cA  = (ll >> 1) & 1;
    const int cB  = cA ^ 1;

    __shared__ unsigned hp[2][2][2][32];    // [par][batch][layer] 64 fp16
    __shared__ float zl[2][768];

    // ---- one-time: pack 4 permuted rows x k-slice -> 32 dwords in AGPRs ----
    unsigned wa[32];
    {
        const float* Wm = (m == 0) ? Whh0 : ((m == 1) ? Wih1 : Whh1);
        const int rofs[4] = { (ll & 1), 2 + (ll & 1), 1 - (ll & 1), 3 - (ll & 1) };
#pragma unroll
        for (int rs = 0; rs < 4; ++rs) {
            const int rr = (4 * q + rofs[rs]) & 255;
            const float4* src = (const float4*)(Wm + rr * 64 + 16 * ll);
            float4 f0 = src[0], f1 = src[1], f2 = src[2], f3 = src[3];
            awrite(wa[8 * rs + 0], packh(f0.x, f0.y));
            awrite(wa[8 * rs + 1], packh(f0.z, f0.w));
            awrite(wa[8 * rs + 2], packh(f1.x, f1.y));
            awrite(wa[8 * rs + 3], packh(f1.z, f1.w));
            awrite(wa[8 * rs + 4], packh(f2.x, f2.y));
            awrite(wa[8 * rs + 5], packh(f2.z, f2.w));
            awrite(wa[8 * rs + 6], packh(f3.x, f3.y));
            awrite(wa[8 * rs + 7], packh(f3.z, f3.w));
        }
    }
    if (tid < 256) ((unsigned*)hp)[tid] = 0;

    // updater role (tid<256)
    const int c_u = tid >> 7;
    const int l_u = (tid >> 6) & 1;
    const int j_u = tid & 63;
    const long bb = (long)blockIdx.x * 2;
    float bias1v[4] = {0, 0, 0, 0};
    float pc[4] = {0, 0, 0, 0};
    const float* pbase_u = pre + (bb + c_u) * (long)(TSTEPS * 256);
    if (tid < 256) {
        if (l_u == 1) {
#pragma unroll
            for (int g = 0; g < 4; ++g) bias1v[g] = bih1[g * 64 + j_u] + bhh1[g * 64 + j_u];
        } else {
#pragma unroll
            for (int g = 0; g < 4; ++g) pc[g] = pbase_u[g * 64 + j_u];   // t=0
        }
    }
    float cst = 0.0f, h1last = 0.0f;
    __syncthreads();

    // one timestep; PAR is a literal at every call site -> static LDS offsets
    auto step = [&](int n, int PAR) {
        // prefetch pre for t=n+1 (layer-0 updaters)
        float pn_[4] = {0, 0, 0, 0};
        if (tid < 256 && l_u == 0) {
            const int tn = (n + 1 < TSTEPS) ? n + 1 : 0;
            const float* pb2 = pbase_u + (long)tn * 256;
#pragma unroll
            for (int g = 0; g < 4; ++g) pn_[g] = pb2[g * 64 + j_u];
        }

        // ---- batch all 32 AGPR reads upfront (one ordered prologue) ----
        uint4 w0[4], w1[4];
#pragma unroll
        for (int rs = 0; rs < 4; ++rs) {
            w0[rs].x = aread(wa[8 * rs + 0]); w0[rs].y = aread(wa[8 * rs + 1]);
            w0[rs].z = aread(wa[8 * rs + 2]); w0[rs].w = aread(wa[8 * rs + 3]);
            w1[rs].x = aread(wa[8 * rs + 4]); w1[rs].y = aread(wa[8 * rs + 5]);
            w1[rs].z = aread(wa[8 * rs + 6]); w1[rs].w = aread(wa[8 * rs + 7]);
        }

        // ---- h slices (static parity offset) ----
        uint4 hA0 = *(const uint4*)&hp[PAR][cA][lay][ll * 8];
        uint4 hA1 = *(const uint4*)&hp[PAR][cA][lay][ll * 8 + 4];
        uint4 hB0 = *(const uint4*)&hp[PAR][cB][lay][ll * 8];
        uint4 hB1 = *(const uint4*)&hp[PAR][cB][lay][ll * 8 + 4];

        // ---- dots (read-free, freely schedulable) ----
        float pA[4], pB[4];
#pragma unroll
        for (int rs = 0; rs < 4; ++rs) {
            pA[rs] = dot16(w0[rs], w1[rs], hA0, hA1);
            pB[rs] = dot16(w0[rs], w1[rs], hB0, hB1);
        }

        float q0A = add_dpp<0xB1>(pA[0], pA[2]);
        float q1A = add_dpp<0xB1>(pA[1], pA[3]);
        float q0B = add_dpp<0xB1>(pB[0], pB[2]);
        float q1B = add_dpp<0xB1>(pB[1], pB[3]);
        float r0 = add_dpp<0x4E>(q0A, q0B);
        float r1 = add_dpp<0x4E>(q1A, q1B);

        const int R0 = 4 * q + (ll & 1);
        zl[cA][R0]     = r0;
        zl[cA][R0 + 2] = r1;
        __syncthreads();   // zl ready

        if (tid < 256) {
            const bool valid = (l_u == 0) ? (n < TSTEPS) : (n >= 1);
            if (valid) {
                float z[4];
                if (l_u == 0) {
#pragma unroll
                    for (int g = 0; g < 4; ++g) z[g] = pc[g] + zl[c_u][g * 64 + j_u];
                } else {
#pragma unroll
                    for (int g = 0; g < 4; ++g)
                        z[g] = bias1v[g] + zl[c_u][256 + g * 64 + j_u] + zl[c_u][512 + g * 64 + j_u];
                }
                float i_ = sigf(z[0]), f_ = sigf(z[1]), g_ = tanh_fast(z[2]), o_ = sigf(z[3]);
                cst = fmaf(f_, cst, i_ * g_);
                float h = o_ * tanh_fast(cst);
                if (l_u) h1last = h;
                ((unsigned short*)&hp[PAR ^ 1][c_u][l_u][0])[j_u] =
                    __builtin_bit_cast(unsigned short, (_Float16)h);
            }
        }
        __syncthreads();   // new h visible
        if (tid < 256 && l_u == 0) {
            pc[0] = pn_[0]; pc[1] = pn_[1]; pc[2] = pn_[2]; pc[3] = pn_[3];
        }
    };

    // 513 steps: pairs with static parity (n even: read 0, write 1; odd: 1->0)
#pragma unroll 1
    for (int i = 0; i < TSTEPS / 2; ++i) {
        step(2 * i,     0);
        step(2 * i + 1, 1);
    }
    step(TSTEPS, 0);   // n=512: layer-1 finishes t=511

    // ---- head: out[bb+c] = h1_{T-1} . Wfc + bfc ----
    if (tid < 256 && l_u == 1) {
        float v = h1last * Wfc[j_u];
#pragma unroll
        for (int off = 32; off > 0; off >>= 1) v += __shfl_down(v, off);
        if (j_u == 0) out[bb + c_u] = v + bfc[0];
    }
}

extern "C" void kernel_launch(void* const* d_in, const int* in_sizes, int n_in,
                              void* d_out, int out_size, void* d_ws, size_t ws_size,
                              hipStream_t stream)
{
    const float* x    = (const float*)d_in[0];
    const float* Wih0 = (const float*)d_in[1];
    const float* Whh0 = (const float*)d_in[2];
    const float* bih0 = (const float*)d_in[3];
    const float* bhh0 = (const float*)d_in[4];
    const float* Wih1 = (const float*)d_in[5];
    const float* Whh1 = (const float*)d_in[6];
    const float* bih1 = (const float*)d_in[7];
    const float* bhh1 = (const float*)d_in[8];
    const float* Wfc  = (const float*)d_in[9];
    const float* bfc  = (const float*)d_in[10];
    float* out = (float*)d_out;
    float* pre = (float*)d_ws;  // [B][T][256] fp32 = 256 MiB

    k_inproj<<<4096, 256, 0, stream>>>(x, Wih0, bih0, bhh0, pre);
    k_fused<<<256, 768, 0, stream>>>(Whh0, Wih1, Whh1, bih1, bhh1, Wfc, bfc, pre, out);
}

// Round 21
// 660.816 us; speedup vs baseline: 1.0540x; 1.0117x over previous
//
#include <hip/hip_runtime.h>

// LSTM B=512,T=512,D=128,H=64,O=1. Gate order i,f,g,o.
// K1: pre = x@Wih0^T + bih0+bhh0 — fp16 MFMA (R15-proven, ~70us).
// K2: HYBRID weight tier — balance DS and VALU pipes.
//   Cross-round model: R13 (all-LDS weights) is DS-pipe-bound (~16 DS/wave/step,
//   VALU 62%); R18-R20 (all-AGPR) are VALU-bound (+32 aread, VALU 77%, DS idle).
//   Each saturates one pipe. Split: rs-slots 0,1 in AGPRs (batched volatile
//   reads, R20 style), rs-slots 2,3 streamed from LDS (R13's conflict-free
//   lane-major uint4 layout, 48KB). DS/wave/step 16->~11, VALU +16 aread into
//   measured idle headroom. Arithmetic byte-identical to R20 (absmax 4.9e-4).
//   Keep R20's static-parity 2-step unroll + layer skew + zl exchange.
// ws: 512*512*256*4 = 256 MiB fp32 pre (written by K1, read-only in K2).

#define TSTEPS 512

typedef _Float16 h2v __attribute__((ext_vector_type(2)));
typedef _Float16 half8 __attribute__((ext_vector_type(8)));
typedef __attribute__((ext_vector_type(4))) float facc;
union HU { unsigned u; h2v h; };

__device__ __forceinline__ float sigf(float x){ return 1.0f/(1.0f+__expf(-x)); }
__device__ __forceinline__ float tanh_fast(float x){
  float ax=fabsf(x); float e=__expf(-2.0f*ax); float r=(1.0f-e)/(1.0f+e); return copysignf(r,x);
}
__device__ __forceinline__ unsigned packh(float a, float b){
  unsigned short la = __builtin_bit_cast(unsigned short, (_Float16)a);
  unsigned short lb = __builtin_bit_cast(unsigned short, (_Float16)b);
  return (unsigned)la | ((unsigned)lb << 16);
}
__device__ __forceinline__ float dot2f(unsigned wu, unsigned hu, float acc){
#if __has_builtin(__builtin_amdgcn_fdot2)
  HU w; w.u = wu; HU x; x.u = hu;
  return __builtin_amdgcn_fdot2(w.h, x.h, acc, false);
#else
  HU w; w.u = wu; HU x; x.u = hu;
  acc = fmaf((float)w.h[0], (float)x.h[0], acc);
  acc = fmaf((float)w.h[1], (float)x.h[1], acc);
  return acc;
#endif
}
template<int CTRL>
__device__ __forceinline__ float add_dpp(float a, float b){
  return a + __int_as_float(__builtin_amdgcn_update_dpp(
      0, __float_as_int(b), CTRL, 0xF, 0xF, true));
}
// two independent 4-fdot2 chains (ILP)
__device__ __forceinline__ float dot16(uint4 w0, uint4 w1, uint4 h0, uint4 h1){
  float a = 0.0f, b = 0.0f;
  a = dot2f(w0.x, h0.x, a); b = dot2f(w0.y, h0.y, b);
  a = dot2f(w0.z, h0.z, a); b = dot2f(w0.w, h0.w, b);
  a = dot2f(w1.x, h1.x, a); b = dot2f(w1.y, h1.y, b);
  a = dot2f(w1.z, h1.z, a); b = dot2f(w1.w, h1.w, b);
  return a + b;
}
// AGPR park/fetch (volatile; reads batched at step top — R20's best variant)
__device__ __forceinline__ void awrite(unsigned &dst, unsigned v){
  asm volatile("v_accvgpr_write_b32 %0, %1" : "=a"(dst) : "v"(v));
}
__device__ __forceinline__ unsigned aread(unsigned &src){
  unsigned r;
  asm volatile("v_accvgpr_read_b32 %0, %1" : "=v"(r) : "a"(src));
  return r;
}

// ---------------- K1: input projection GEMM (fp16 MFMA, R15) ----------------
__global__ __launch_bounds__(256) void k_inproj(
    const float* __restrict__ x, const float* __restrict__ W,
    const float* __restrict__ bih, const float* __restrict__ bhh,
    float* __restrict__ pre)
{
    __shared__ __align__(16) _Float16 Ah[64][136];
    __shared__ __align__(16) _Float16 Bh[256][136];
    const int tid = threadIdx.x;
    const long row0 = (long)blockIdx.x * 64;

    {
        const int r = tid >> 2, c0 = (tid & 3) * 32;
        const float4* src = (const float4*)(x + (row0 + r) * 128 + c0);
#pragma unroll
        for (int i = 0; i < 4; ++i) {
            float4 v0 = src[2 * i], v1 = src[2 * i + 1];
            half8 hv = { (_Float16)v0.x, (_Float16)v0.y, (_Float16)v0.z, (_Float16)v0.w,
                         (_Float16)v1.x, (_Float16)v1.y, (_Float16)v1.z, (_Float16)v1.w };
            *(half8*)&Ah[r][c0 + 8 * i] = hv;
        }
    }
    {
        const float4* src = (const float4*)(W + tid * 128);
#pragma unroll
        for (int i = 0; i < 16; ++i) {
            float4 v0 = src[2 * i], v1 = src[2 * i + 1];
            half8 hv = { (_Float16)v0.x, (_Float16)v0.y, (_Float16)v0.z, (_Float16)v0.w,
                         (_Float16)v1.x, (_Float16)v1.y, (_Float16)v1.z, (_Float16)v1.w };
            *(half8*)&Bh[tid][8 * i] = hv;
        }
    }
    __syncthreads();

    const int w  = tid >> 6;
    const int l  = tid & 63;
    const int lm = l & 15;
    const int lk = l >> 4;
    const int n0 = w * 64;

    facc acc[4][4];
#pragma unroll
    for (int mi = 0; mi < 4; ++mi)
#pragma unroll
        for (int ni = 0; ni < 4; ++ni) acc[mi][ni] = (facc){0.f, 0.f, 0.f, 0.f};

#pragma unroll
    for (int ks = 0; ks < 4; ++ks) {
        const int kk = ks * 32 + lk * 8;
        half8 Af[4], Bf[4];
#pragma unroll
        for (int mi = 0; mi < 4; ++mi) Af[mi] = *(const half8*)&Ah[mi * 16 + lm][kk];
#pragma unroll
        for (int ni = 0; ni < 4; ++ni) Bf[ni] = *(const half8*)&Bh[n0 + ni * 16 + lm][kk];
#pragma unroll
        for (int mi = 0; mi < 4; ++mi)
#pragma unroll
            for (int ni = 0; ni < 4; ++ni)
                acc[mi][ni] = __builtin_amdgcn_mfma_f32_16x16x32_f16(
                    Af[mi], Bf[ni], acc[mi][ni], 0, 0, 0);
    }

    float bs[4];
#pragma unroll
    for (int ni = 0; ni < 4; ++ni) {
        const int n = n0 + ni * 16 + lm;
        bs[ni] = bih[n] + bhh[n];
    }
#pragma unroll
    for (int mi = 0; mi < 4; ++mi) {
#pragma unroll
        for (int ni = 0; ni < 4; ++ni) {
            const int n = n0 + ni * 16 + lm;
#pragma unroll
            for (int r = 0; r < 4; ++r) {
                const long row = row0 + mi * 16 + lk * 4 + r;
                pre[row * 256 + n] = acc[mi][ni][r] + bs[ni];
            }
        }
    }
}

// ---------------- K2: fused 2-layer recurrence + head (hybrid weights) ------
__global__
__attribute__((amdgpu_flat_work_group_size(768, 768)))
__attribute__((amdgpu_waves_per_eu(3)))
void k_fused(
    const float* __restrict__ Whh0, const float* __restrict__ Wih1,
    const float* __restrict__ Whh1,
    const float* __restrict__ bih1, const float* __restrict__ bhh1,
    const float* __restrict__ Wfc,  const float* __restrict__ bfc,
    const float* __restrict__ pre,  float* __restrict__ out)
{
    const int tid = threadIdx.x;
    const int ll  = tid & 3;
    const int q   = tid >> 2;
    const int m   = q >> 6;           // matrix: 0=Whh0, 1=Wih1, 2=Whh1
    const int lay = (m == 2) ? 1 : 0;
    const int cA  = (ll >> 1) & 1;
    const int cB  = cA ^ 1;

    __shared__ __align__(16) uint4 wlh[4][768];   // 48KB: rs=2,3 weight streams
    __shared__ unsigned hp[2][2][2][32];          // [par][batch][layer] 64 fp16
    __shared__ float zl[2][768];

    // ---- one-time: rs 0,1 -> AGPRs; rs 2,3 -> LDS streams ----
    unsigned wa[16];
    {
        const float* Wm = (m == 0) ? Whh0 : ((m == 1) ? Wih1 : Whh1);
        const int rofs[4] = { (ll & 1), 2 + (ll & 1), 1 - (ll & 1), 3 - (ll & 1) };
#pragma unroll
        for (int rs = 0; rs < 4; ++rs) {
            const int rr = (4 * q + rofs[rs]) & 255;
            const float4* src = (const float4*)(Wm + rr * 64 + 16 * ll);
            float4 f0 = src[0], f1 = src[1], f2 = src[2], f3 = src[3];
            if (rs < 2) {
                awrite(wa[8 * rs + 0], packh(f0.x, f0.y));
                awrite(wa[8 * rs + 1], packh(f0.z, f0.w));
                awrite(wa[8 * rs + 2], packh(f1.x, f1.y));
                awrite(wa[8 * rs + 3], packh(f1.z, f1.w));
                awrite(wa[8 * rs + 4], packh(f2.x, f2.y));
                awrite(wa[8 * rs + 5], packh(f2.z, f2.w));
                awrite(wa[8 * rs + 6], packh(f3.x, f3.y));
                awrite(wa[8 * rs + 7], packh(f3.z, f3.w));
            } else {
                uint4 u0 = { packh(f0.x,f0.y), packh(f0.z,f0.w), packh(f1.x,f1.y), packh(f1.z,f1.w) };
                uint4 u1 = { packh(f2.x,f2.y), packh(f2.z,f2.w), packh(f3.x,f3.y), packh(f3.z,f3.w) };
                wlh[2 * (rs - 2) + 0][tid] = u0;
                wlh[2 * (rs - 2) + 1][tid] = u1;
            }
        }
    }
    if (tid < 256) ((unsigned*)hp)[tid] = 0;

    // updater role (tid<256)
    const int c_u = tid >> 7;
    const int l_u = (tid >> 6) & 1;
    const int j_u = tid & 63;
    const long bb = (long)blockIdx.x * 2;
    float bias1v[4] = {0, 0, 0, 0};
    float pc[4] = {0, 0, 0, 0};
    const float* pbase_u = pre + (bb + c_u) * (long)(TSTEPS * 256);
    if (tid < 256) {
        if (l_u == 1) {
#pragma unroll
            for (int g = 0; g < 4; ++g) bias1v[g] = bih1[g * 64 + j_u] + bhh1[g * 64 + j_u];
        } else {
#pragma unroll
            for (int g = 0; g < 4; ++g) pc[g] = pbase_u[g * 64 + j_u];   // t=0
        }
    }
    float cst = 0.0f, h1last = 0.0f;
    __syncthreads();

    // one timestep; PAR is a literal at every call site -> static LDS offsets
    auto step = [&](int n, int PAR) {
        // prefetch pre for t=n+1 (layer-0 updaters)
        float pn_[4] = {0, 0, 0, 0};
        if (tid < 256 && l_u == 0) {
            const int tn = (n + 1 < TSTEPS) ? n + 1 : 0;
            const float* pb2 = pbase_u + (long)tn * 256;
#pragma unroll
            for (int g = 0; g < 4; ++g) pn_[g] = pb2[g * 64 + j_u];
        }

        uint4 w0[4], w1[4];
        // LDS half first (DS pipe; latency overlaps the aread batch below)
        w0[2] = wlh[0][tid]; w1[2] = wlh[1][tid];
        w0[3] = wlh[2][tid]; w1[3] = wlh[3][tid];
        // h slices (static parity offset)
        uint4 hA0 = *(const uint4*)&hp[PAR][cA][lay][ll * 8];
        uint4 hA1 = *(const uint4*)&hp[PAR][cA][lay][ll * 8 + 4];
        uint4 hB0 = *(const uint4*)&hp[PAR][cB][lay][ll * 8];
        uint4 hB1 = *(const uint4*)&hp[PAR][cB][lay][ll * 8 + 4];
        // AGPR half (VALU pipe, batched volatile reads)
#pragma unroll
        for (int rs = 0; rs < 2; ++rs) {
            w0[rs].x = aread(wa[8 * rs + 0]); w0[rs].y = aread(wa[8 * rs + 1]);
            w0[rs].z = aread(wa[8 * rs + 2]); w0[rs].w = aread(wa[8 * rs + 3]);
            w1[rs].x = aread(wa[8 * rs + 4]); w1[rs].y = aread(wa[8 * rs + 5]);
            w1[rs].z = aread(wa[8 * rs + 6]); w1[rs].w = aread(wa[8 * rs + 7]);
        }

        // ---- dots ----
        float pA[4], pB[4];
#pragma unroll
        for (int rs = 0; rs < 4; ++rs) {
            pA[rs] = dot16(w0[rs], w1[rs], hA0, hA1);
            pB[rs] = dot16(w0[rs], w1[rs], hB0, hB1);
        }

        float q0A = add_dpp<0xB1>(pA[0], pA[2]);
        float q1A = add_dpp<0xB1>(pA[1], pA[3]);
        float q0B = add_dpp<0xB1>(pB[0], pB[2]);
        float q1B = add_dpp<0xB1>(pB[1], pB[3]);
        float r0 = add_dpp<0x4E>(q0A, q0B);
        float r1 = add_dpp<0x4E>(q1A, q1B);

        const int R0 = 4 * q + (ll & 1);
        zl[cA][R0]     = r0;
        zl[cA][R0 + 2] = r1;
        __syncthreads();   // zl ready

        if (tid < 256) {
            const bool valid = (l_u == 0) ? (n < TSTEPS) : (n >= 1);
            if (valid) {
                float z[4];
                if (l_u == 0) {
#pragma unroll
                    for (int g = 0; g < 4; ++g) z[g] = pc[g] + zl[c_u][g * 64 + j_u];
                } else {
#pragma unroll
                    for (int g = 0; g < 4; ++g)
                        z[g] = bias1v[g] + zl[c_u][256 + g * 64 + j_u] + zl[c_u][512 + g * 64 + j_u];
                }
                float i_ = sigf(z[0]), f_ = sigf(z[1]), g_ = tanh_fast(z[2]), o_ = sigf(z[3]);
                cst = fmaf(f_, cst, i_ * g_);
                float h = o_ * tanh_fast(cst);
                if (l_u) h1last = h;
                ((unsigned short*)&hp[PAR ^ 1][c_u][l_u][0])[j_u] =
                    __builtin_bit_cast(unsigned short, (_Float16)h);
            }
        }
        __syncthreads();   // new h visible
        if (tid < 256 && l_u == 0) {
            pc[0] = pn_[0]; pc[1] = pn_[1]; pc[2] = pn_[2]; pc[3] = pn_[3];
        }
    };

    // 513 steps: pairs with static parity
#pragma unroll 1
    for (int i = 0; i < TSTEPS / 2; ++i) {
        step(2 * i,     0);
        step(2 * i + 1, 1);
    }
    step(TSTEPS, 0);   // n=512: layer-1 finishes t=511

    // ---- head: out[bb+c] = h1_{T-1} . Wfc + bfc ----
    if (tid < 256 && l_u == 1) {
        float v = h1last * Wfc[j_u];
#pragma unroll
        for (int off = 32; off > 0; off >>= 1) v += __shfl_down(v, off);
        if (j_u == 0) out[bb + c_u] = v + bfc[0];
    }
}

extern "C" void kernel_launch(void* const* d_in, const int* in_sizes, int n_in,
                              void* d_out, int out_size, void* d_ws, size_t ws_size,
                              hipStream_t stream)
{
    const float* x    = (const float*)d_in[0];
    const float* Wih0 = (const float*)d_in[1];
    const float* Whh0 = (const float*)d_in[2];
    const float* bih0 = (const float*)d_in[3];
    const float* bhh0 = (const float*)d_in[4];
    const float* Wih1 = (const float*)d_in[5];
    const float* Whh1 = (const float*)d_in[6];
    const float* bih1 = (const float*)d_in[7];
    const float* bhh1 = (const float*)d_in[8];
    const float* Wfc  = (const float*)d_in[9];
    const float* bfc  = (const float*)d_in[10];
    float* out = (float*)d_out;
    float* pre = (float*)d_ws;  // [B][T][256] fp32 = 256 MiB

    k_inproj<<<4096, 256, 0, stream>>>(x, Wih0, bih0, bhh0, pre);
    k_fused<<<256, 768, 0, stream>>>(Whh0, Wih1, Whh1, bih1, bhh1, Wfc, bfc, pre, out);
}